// Round 9
// baseline (228.423 us; speedup 1.0000x reference)
//
#include <hip/hip_runtime.h>
#include <hip/hip_bf16.h>

// B=16384 W=5 L=20 E=50 V=100000 C=128 H=4096 O=50
// ha   = bf16 [16384][256] (K: 250 data + [250]=1.0 bias + pad)  ws+0     (8 MB)
// wbf  = bf16 fc1 weights in MFMA A-frag layout:                 ws+8M    (2 MB)
// w2bf = bf16 fc2 weights in MFMA B-frag layout:                 ws+10M   (0.5 MB)
// gt   = fp32 [128][156]                                         ws+11M   (78 KB)
// gpart= fp32 [512][64][64] fc2 logit partials (per kh-half)     ws+16M   (8 MB)
// R8 post-mortem: fused stuck at ~6.3k cyc/chunk vs ~2.4k port-bound work --
// per-chunk __syncthreads lockstep + 1 block/CU (144KB LDS) exposes all
// serialization; dbuf/async/unroll all returned <=3%.
// R9: BARRIER-FREE main loop. B read per-wave straight from L2 into regs
// (wbf is L2-resident; drop Bs + gload_lds + all loop barriers). 256-thr
// blocks (4 waves), wave = 32 rows x 64 cols, 512 blocks = 2 blocks/CU,
// LDS 48KB (hs 16K + part 32K). hs handoff stays wave-private (R7-proven).
// Compiler is free to hoist next-chunk loads under tanh/fc2; co-resident
// block covers the rest.

typedef __attribute__((ext_vector_type(8))) short short8;
typedef __attribute__((ext_vector_type(4))) float float4v;

__device__ inline short bf16b(float f) {
    __hip_bfloat16 h = __float2bfloat16(f);
    return *reinterpret_cast<short*>(&h);
}
__device__ inline uint packbf2(float a, float b) {
    return (uint)(ushort)bf16b(a) | ((uint)(ushort)bf16b(b) << 16);
}

// ---------------------------------------------------------------------------
// Merged prep: wbf (blocks 0..4095), w2bf (..5119), gt (..5194), haPad (..5578)
// ---------------------------------------------------------------------------
__global__ __launch_bounds__(256) void prep_kernel(
    const float* __restrict__ fc1_w, const float* __restrict__ fc1_b,
    const float* __restrict__ fc2_w, const float* __restrict__ char_emb,
    const float* __restrict__ conv_w, short* __restrict__ wbf,
    short* __restrict__ w2bf, float* __restrict__ gt,
    __hip_bfloat16* __restrict__ ha)
{
    const int bid = blockIdx.x;
    if (bid < 4096) {                       // fc1 weights+bias -> frag order
        int idx = bid * 256 + threadIdx.x;  // n*256 + k
        int n = idx >> 8, k = idx & 255;
        float v = (k < 250) ? fc1_w[n * 250 + k] : (k == 250 ? fc1_b[n] : 0.f);
        int CT = n >> 4, mm = n & 15;
        int ks = k >> 5, qq = (k >> 3) & 3, j = k & 7;
        wbf[((CT * 8 + ks) * 64 + qq * 16 + mm) * 8 + j] = bf16b(v);
    } else if (bid < 5120) {                // fc2 weights (pad 64) -> frag order
        int idx = (bid - 4096) * 256 + threadIdx.x;   // o*4096 + k
        int o = idx >> 12, k = idx & 4095;
        float v = (o < 50) ? fc2_w[idx] : 0.f;
        int Ot = o >> 4, mm = o & 15;
        int kst = k >> 5, qq = (k >> 3) & 3, j = k & 7;
        w2bf[((kst * 4 + Ot) * 64 + qq * 16 + mm) * 8 + j] = bf16b(v);
    } else if (bid < 5195) {                // conv lookup table
        int idx = (bid - 5120) * 256 + threadIdx.x;   // < 19200
        if (idx >= 19200) return;
        int c = idx / 150, rem = idx - c * 150;
        int kk = rem / 50, o = rem - kk * 50;
        const float* ce = char_emb + c * 50;
        const float* w  = conv_w + o * 150 + kk;
        float s = 0.f;
        #pragma unroll 10
        for (int i = 0; i < 50; ++i) s += ce[i] * w[i * 3];
        gt[c * 156 + kk * 52 + o] = s;
    } else {                                // ha pad cols 250..255
        int idx = (bid - 5195) * 256 + threadIdx.x;   // b*6 + j
        int b = idx / 6, j = idx - b * 6;
        ha[b * 256 + 250 + j] = __float2bfloat16(j == 0 ? 1.f : 0.f);
    }
}

// ---------------------------------------------------------------------------
// conv v2 (R8, passed): one channel per lane, conflict-free scalar LDS reads.
// 640 blocks x 512 thr; block = 128 words; char ids packed into Gs pad holes.
// ---------------------------------------------------------------------------
__global__ __launch_bounds__(512) void conv_kernel(
    const int* __restrict__ x, const int* __restrict__ wci,
    const float* __restrict__ word_emb, const float* __restrict__ conv_b,
    const float* __restrict__ gt, __hip_bfloat16* __restrict__ ha)
{
    __shared__ float Gs[19968];           // 78 KiB -> 2 blocks/CU
    char* gsb = (char*)Gs;

    const int tid = threadIdx.x;
    const int gw0 = blockIdx.x * 128;

    #pragma unroll
    for (int t = 0; t < 39; ++t)
        Gs[t * 512 + tid] = gt[t * 512 + tid];
    __syncthreads();                       // rows (incl. pad holes) staged

    // pack char ids + xid into the pad holes of row `word`
    {
        const int word = tid >> 2, part = tid & 3;
        const int xid = x[gw0 + word];
        const int* crow = wci + (size_t)xid * 20 + part * 5;
        char* hole = gsb + word * 624;
        #pragma unroll
        for (int j = 0; j < 5; ++j) {
            const int p = part * 5 + j;
            const int off = (p < 8) ? 200 + p : (p < 16 ? 400 + p : 600 + p);
            hole[off] = (char)crow[j];
        }
        if (part == 0) *(int*)(hole + 620) = xid;
    }
    __syncthreads();

    const int lane = tid & 63;
    const int wv   = tid >> 6;
    const int oc   = (lane < 50) ? lane : 49;   // clamp keeps reads in-bounds
    const int oc4  = oc * 4;
    const float cbias = conv_b[oc];

    for (int it = 0; it < 16; ++it) {
        const int wl = it * 8 + wv;
        const char* hb = gsb + wl * 624;
        const uint cw0 = *(const uint*)(hb + 200);
        const uint cw1 = *(const uint*)(hb + 204);
        const uint cw2 = *(const uint*)(hb + 408);
        const uint cw3 = *(const uint*)(hb + 412);
        const uint cw4 = *(const uint*)(hb + 616);
        const int xid  = *(const int*)(hb + 620);

        int cb[20];
        #pragma unroll
        for (int p = 0; p < 20; ++p) {
            const uint cwv = (p < 4) ? cw0 : (p < 8) ? cw1 : (p < 12) ? cw2
                           : (p < 16) ? cw3 : cw4;
            const int c = (int)((cwv >> ((p & 3) * 8)) & 0xFF);
            cb[p] = c * 624 + oc4;
        }

        float mx = *(const float*)(gsb + cb[0] + 208)
                 + *(const float*)(gsb + cb[1] + 416);
        #pragma unroll
        for (int l = 1; l < 19; ++l) {
            float s = *(const float*)(gsb + cb[l] + 208)
                    + *(const float*)(gsb + cb[l - 1])
                    + *(const float*)(gsb + cb[l + 1] + 416);
            mx = fmaxf(mx, s);
        }
        {
            float s = *(const float*)(gsb + cb[19] + 208)
                    + *(const float*)(gsb + cb[18]);
            mx = fmaxf(mx, s);
        }

        const float wer = word_emb[(size_t)xid * 50 + oc];
        const float res = mx + cbias + wer;
        const int gw = gw0 + wl;
        const int b = gw / 5, wp = gw - b * 5;
        if (lane < 50)
            ha[b * 256 + wp * 50 + lane] = __float2bfloat16(res);
    }
}

// ---------------------------------------------------------------------------
// Fused fc1 + tanh + fc2-partial, BARRIER-FREE main loop.
// 512 blocks x 256 thr (4 waves). Block = (rg = bid>>1: 64 rows) x
// (kh = bid&1: 16 chunks of 128 h-cols).
// Waves 2x2: wr = wv>>1 (row half, 32 rows), wc2 = wv&1 (col half, 64 cols
// = col-tiles nt 0..3 = fc2 k-frags kf = wc2*2 + (nt>>1)).
// bv/b2 loaded straight from L2 (no Bs, no gload_lds, no loop barriers);
// hs handoff wave-private (same-wave LDS RAW ordered by HW).
// acc2 accumulates BOTH of the wave's k-frags; 2 partials (wc2) reduced in
// the epilogue (one barrier), then gpart. LDS = part 32KB + hs 16KB = 48KB.
// ---------------------------------------------------------------------------
__global__ __launch_bounds__(256, 2) void fused_kernel(
    const __hip_bfloat16* __restrict__ ha, const short* __restrict__ wbf,
    const short* __restrict__ w2bf, float* __restrict__ gpart)
{
    __shared__ char smem[49152];                 // 48 KB
    float* partf = (float*)smem;                 // [2][64][64] (32 KB)
    char*  hsb   = smem + 32768;                 // 16 KB (16 frags)

    const int tid  = threadIdx.x;
    const int lane = tid & 63;
    const int wv   = tid >> 6;
    const int wr = wv >> 1, wc2 = wv & 1;
    const int q = lane >> 4, m = lane & 15;
    const int rg = blockIdx.x >> 1, kh = blockIdx.x & 1;
    const int m0 = rg * 64;
    const int q2base = q >> 1, slot = q & 1;

    const short8* wbfv  = (const short8*)wbf;
    const short8* w2bfv = (const short8*)w2bf;
    const short8* hav   = (const short8*)ha;

    // ---- A-frags: wave's 32 rows x K=256: 16 frags = 64 VGPR, pinned ----
    short8 av[2][8];
    #pragma unroll
    for (int mt = 0; mt < 2; ++mt)
        #pragma unroll
        for (int ks = 0; ks < 8; ++ks)
            av[mt][ks] = hav[(size_t)(m0 + wr * 32 + mt * 16 + m) * 32 + ks * 4 + q];
    #pragma unroll
    for (int mt = 0; mt < 2; ++mt)
        #pragma unroll
        for (int ks = 0; ks < 8; ++ks)
            asm volatile("" : "+v"(av[mt][ks]));

    float4v acc2[2][4] = {};    // fc2 partial: [row-tile mt][out-tile]

    for (int chl = 0; chl < 16; ++chl) {
        const int chg = kh * 16 + chl;

        // ---- fc1: rows [wr*32,+32) x cols [chg*128 + wc2*64, +64) ----
        // bv straight from L2: col-tile CT = chg*8 + wc2*4 + nt
        float4v acc[2][4] = {};
        #pragma unroll
        for (int ks = 0; ks < 8; ++ks) {
            short8 bv[4];
            #pragma unroll
            for (int nt = 0; nt < 4; ++nt)
                bv[nt] = wbfv[(size_t)((chg * 8 + wc2 * 4 + nt) * 8 + ks) * 64 + lane];
            #pragma unroll
            for (int mt = 0; mt < 2; ++mt)
                #pragma unroll
                for (int nt = 0; nt < 4; ++nt)
                    acc[mt][nt] = __builtin_amdgcn_mfma_f32_16x16x32_bf16(
                        bv[nt], av[mt][ks], acc[mt][nt], 0, 0, 0);
        }

        // ---- tanh + pack to own hs frags (rt = wr*2+mt, kf = wc2*2+(nt>>1)) ----
        #pragma unroll
        for (int mt = 0; mt < 2; ++mt) {
            #pragma unroll
            for (int nt = 0; nt < 4; ++nt) {
                float tv[4];
                #pragma unroll
                for (int r = 0; r < 4; ++r)
                    tv[r] = 1.f - 2.f / (__expf(2.f * acc[mt][nt][r]) + 1.f);
                const int frag = (wr * 2 + mt) * 4 + wc2 * 2 + (nt >> 1);
                const int q2 = (nt & 1) * 2 + q2base;
                const uint p0 = packbf2(tv[0], tv[1]);
                const uint p1 = packbf2(tv[2], tv[3]);
                *(uint2*)(hsb + ((frag * 64 + q2 * 16 + m) * 16 + slot * 8))
                    = make_uint2(p0, p1);
            }
        }

        // ---- fc2 partial: both of the wave's k-frags, own hs (no barrier) ----
        #pragma unroll
        for (int kf2 = 0; kf2 < 2; ++kf2) {
            const int kf = wc2 * 2 + kf2;
            short8 b2[4], a2[2];
            #pragma unroll
            for (int Ot = 0; Ot < 4; ++Ot)
                b2[Ot] = w2bfv[(size_t)((chg * 4 + kf) * 4 + Ot) * 64 + lane];
            #pragma unroll
            for (int mt = 0; mt < 2; ++mt)
                a2[mt] = *(const short8*)(hsb
                    + (((wr * 2 + mt) * 4 + kf) * 64 + lane) * 16);
            #pragma unroll
            for (int mt = 0; mt < 2; ++mt)
                #pragma unroll
                for (int Ot = 0; Ot < 4; ++Ot)
                    acc2[mt][Ot] = __builtin_amdgcn_mfma_f32_16x16x32_bf16(
                        a2[mt], b2[Ot], acc2[mt][Ot], 0, 0, 0);
        }
        // no __syncthreads: hs is wave-private, B comes from L2, waves free-run
    }

    // ---- epilogue: spill the 2 wc2 k-partials, reduce, write gpart ----
    // (hs reads of the last chunk are same-wave-ordered before these writes;
    //  partf region [0,32K) is disjoint from hsb [32K,48K))
    #pragma unroll
    for (int mt = 0; mt < 2; ++mt)
        #pragma unroll
        for (int Ot = 0; Ot < 4; ++Ot)
            #pragma unroll
            for (int r = 0; r < 4; ++r)
                partf[(size_t)wc2 * 4096
                      + ((wr * 2 + mt) * 16 + q * 4 + r) * 64 + Ot * 16 + m]
                    = acc2[mt][Ot][r];
    __syncthreads();

    #pragma unroll
    for (int t = 0; t < 16; ++t) {
        int idx = t * 256 + tid;           // row*64 + col
        float s = partf[idx] + partf[4096 + idx];
        gpart[(size_t)blockIdx.x * 4096 + idx] = s;
    }
}

// ---------------------------------------------------------------------------
// combine: sum the two kh halves, + bias, softmax, write out.
// ---------------------------------------------------------------------------
__global__ __launch_bounds__(256) void combine_kernel(
    const float* __restrict__ gpart, const float* __restrict__ fc2_b,
    float* __restrict__ out)
{
    const int tid  = threadIdx.x;
    const int lane = tid & 63;
    const int wv   = tid >> 6;
    const float bias = (lane < 50) ? fc2_b[lane] : 0.f;

    #pragma unroll
    for (int rr = 0; rr < 8; ++rr) {
        const int row = blockIdx.x * 32 + wv * 8 + rr;
        const int rg = row >> 6, rl = row & 63;
        float v = gpart[(size_t)(rg * 2) * 4096 + rl * 64 + lane]
                + gpart[(size_t)(rg * 2 + 1) * 4096 + rl * 64 + lane];
        v = (lane < 50) ? v + bias : -1e30f;
        float mx = v;
        #pragma unroll
        for (int off = 32; off > 0; off >>= 1) mx = fmaxf(mx, __shfl_xor(mx, off));
        float e = __expf(v - mx);
        float s = e;
        #pragma unroll
        for (int off = 32; off > 0; off >>= 1) s += __shfl_xor(s, off);
        if (lane < 50)
            out[(size_t)row * 50 + lane] = e / s;
    }
}

// ---------------------------------------------------------------------------
extern "C" void kernel_launch(void* const* d_in, const int* in_sizes, int n_in,
                              void* d_out, int out_size, void* d_ws, size_t ws_size,
                              hipStream_t stream) {
    const int*   x        = (const int*)  d_in[0];
    const int*   wci      = (const int*)  d_in[1];
    const float* word_emb = (const float*)d_in[2];
    const float* char_emb = (const float*)d_in[3];
    const float* conv_w   = (const float*)d_in[4];
    const float* conv_b   = (const float*)d_in[5];
    const float* fc1_w    = (const float*)d_in[6];
    const float* fc1_b    = (const float*)d_in[7];
    const float* fc2_w    = (const float*)d_in[8];
    const float* fc2_b    = (const float*)d_in[9];
    float* out = (float*)d_out;

    char* ws = (char*)d_ws;
    __hip_bfloat16* ha  = (__hip_bfloat16*)ws;                        // 8 MB
    short* wbf   = (short*)(ws + ((size_t)8  << 20));                 // 2 MB
    short* w2bf  = (short*)(ws + ((size_t)10 << 20));                 // 0.5 MB
    float* gtp   = (float*)(ws + ((size_t)11 << 20));                 // 78 KB
    float* gpart = (float*)(ws + ((size_t)16 << 20));                 // 8 MB

    prep_kernel<<<5579, 256, 0, stream>>>(fc1_w, fc1_b, fc2_w, char_emb,
                                          conv_w, wbf, w2bf, gtp, ha);
    conv_kernel<<<640, 512, 0, stream>>>(x, wci, word_emb, conv_b, gtp, ha);
    fused_kernel<<<512, 256, 0, stream>>>(ha, wbf, w2bf, gpart);
    combine_kernel<<<512, 256, 0, stream>>>(gpart, fc2_b, out);
}

// Round 10
// 205.101 us; speedup vs baseline: 1.1137x; 1.1137x over previous
//
#include <hip/hip_runtime.h>
#include <hip/hip_bf16.h>

// B=16384 W=5 L=20 E=50 V=100000 C=128 H=4096 O=50
// ha   = bf16 [16384][256] (K: 250 data + [250]=1.0 bias + pad)  ws+0     (8 MB)
// wbf  = bf16 fc1 weights in MFMA A-frag layout:                 ws+8M    (2 MB)
// w2bf = bf16 fc2 weights in MFMA B-frag layout:                 ws+10M   (0.5 MB)
// gt2  = fp32 [128][50][3] conv table, {kk0,kk1,kk2} per (c,oc)  ws+11M   (77 KB)
// gpart= fp32 [512][64][64] fc2 logit partials (per kh-half)     ws+16M   (8 MB)
// R9 post-mortem: barrier-free fused REGRESSED 83.5->102 (per-wave B from L2
// = 320KB/chunk/CU ~ 5.7k cyc at 56B/cyc -- L2-BW wall; LDS-staged B is
// right). R8 fused restored verbatim (83.5us best).
// R10: conv was LDS-INSTRUCTION-bound: 58 scalar b32 taps/word x 81920 words
// = 4.75M wave-instrs ~ 45us (3x its 14us byte floor). Repack table as
// [c][oc]{kk0,kk1,kk2} (12B stride): 20 reads/word (S_l = r[l].y + r[l-1].x
// + r[l+1].z, same FP order); stride-3 float-index -> banks {3oc..+2}
// disjoint per phase = conflict-free. Everything else identical to R8.

typedef __attribute__((ext_vector_type(8))) short short8;
typedef __attribute__((ext_vector_type(4))) float float4v;

__device__ inline short bf16b(float f) {
    __hip_bfloat16 h = __float2bfloat16(f);
    return *reinterpret_cast<short*>(&h);
}
__device__ inline uint packbf2(float a, float b) {
    return (uint)(ushort)bf16b(a) | ((uint)(ushort)bf16b(b) << 16);
}
__device__ inline void gload_lds16(const void* g, void* l) {
    __builtin_amdgcn_global_load_lds(
        (const __attribute__((address_space(1))) unsigned int*)g,
        (__attribute__((address_space(3))) unsigned int*)l, 16, 0, 0);
}

struct F3 { float x, y, z; };

// ---------------------------------------------------------------------------
// Merged prep: wbf (blocks 0..4095), w2bf (..5119), gt2 (..5194), haPad (..5578)
// ---------------------------------------------------------------------------
__global__ __launch_bounds__(256) void prep_kernel(
    const float* __restrict__ fc1_w, const float* __restrict__ fc1_b,
    const float* __restrict__ fc2_w, const float* __restrict__ char_emb,
    const float* __restrict__ conv_w, short* __restrict__ wbf,
    short* __restrict__ w2bf, float* __restrict__ gt2,
    __hip_bfloat16* __restrict__ ha)
{
    const int bid = blockIdx.x;
    if (bid < 4096) {                       // fc1 weights+bias -> frag order
        int idx = bid * 256 + threadIdx.x;  // n*256 + k
        int n = idx >> 8, k = idx & 255;
        float v = (k < 250) ? fc1_w[n * 250 + k] : (k == 250 ? fc1_b[n] : 0.f);
        int CT = n >> 4, mm = n & 15;
        int ks = k >> 5, qq = (k >> 3) & 3, j = k & 7;
        wbf[((CT * 8 + ks) * 64 + qq * 16 + mm) * 8 + j] = bf16b(v);
    } else if (bid < 5120) {                // fc2 weights (pad 64) -> frag order
        int idx = (bid - 4096) * 256 + threadIdx.x;   // o*4096 + k
        int o = idx >> 12, k = idx & 4095;
        float v = (o < 50) ? fc2_w[idx] : 0.f;
        int Ot = o >> 4, mm = o & 15;
        int kst = k >> 5, qq = (k >> 3) & 3, j = k & 7;
        w2bf[((kst * 4 + Ot) * 64 + qq * 16 + mm) * 8 + j] = bf16b(v);
    } else if (bid < 5195) {                // conv table -> [c][oc][kk] layout
        int idx = (bid - 5120) * 256 + threadIdx.x;   // < 19200
        if (idx >= 19200) return;
        int c = idx / 150, rem = idx - c * 150;
        int kk = rem / 50, o = rem - kk * 50;
        const float* ce = char_emb + c * 50;
        const float* w  = conv_w + o * 150 + kk;
        float s = 0.f;
        #pragma unroll 10
        for (int i = 0; i < 50; ++i) s += ce[i] * w[i * 3];
        gt2[(c * 50 + o) * 3 + kk] = s;
    } else {                                // ha pad cols 250..255
        int idx = (bid - 5195) * 256 + threadIdx.x;   // b*6 + j
        int b = idx / 6, j = idx - b * 6;
        ha[b * 256 + 250 + j] = __float2bfloat16(j == 0 ? 1.f : 0.f);
    }
}

// ---------------------------------------------------------------------------
// conv v3: 12B {kk0,kk1,kk2} taps -> 20 LDS reads per word (was 58).
// 640 blocks x 512 thr; block = 128 words; wave handles word wl = it*8+wv.
// Banks: float-index (c*50+oc)*3, stride 3 per lane -> {3oc,3oc+1,3oc+2}
// disjoint partition per 32-lane phase = conflict-free.
// ---------------------------------------------------------------------------
__global__ __launch_bounds__(512, 4) void conv_kernel(
    const int* __restrict__ x, const int* __restrict__ wci,
    const float* __restrict__ word_emb, const float* __restrict__ conv_b,
    const float* __restrict__ gt2, __hip_bfloat16* __restrict__ ha)
{
    __shared__ float Gs[19200];           // 75 KiB table
    __shared__ uint  cpack[640];          // 128 words x 5 packed ids
    __shared__ int   xs[128];
    char* gsb = (char*)Gs;

    const int tid = threadIdx.x;
    const int gw0 = blockIdx.x * 128;

    #pragma unroll
    for (int t = 0; t < 38; ++t) {
        int idx = t * 512 + tid;
        if (idx < 19200) Gs[idx] = gt2[idx];
    }

    if (tid < 128) {
        const int xid = x[gw0 + tid];
        xs[tid] = xid;
        const int* crow = wci + (size_t)xid * 20;
        int cid[20];
        #pragma unroll
        for (int p = 0; p < 20; ++p) cid[p] = crow[p];
        #pragma unroll
        for (int u = 0; u < 5; ++u)
            cpack[tid * 5 + u] = (uint)cid[u * 4] | ((uint)cid[u * 4 + 1] << 8)
                               | ((uint)cid[u * 4 + 2] << 16) | ((uint)cid[u * 4 + 3] << 24);
    }
    __syncthreads();

    const int lane = tid & 63;
    const int wv   = tid >> 6;
    const int oc   = (lane < 50) ? lane : 49;   // clamp keeps reads in-bounds
    const int oc12 = oc * 12;                    // byte offset within row
    const float cbias = conv_b[oc];

    for (int it = 0; it < 16; ++it) {
        const int wl = it * 8 + wv;
        uint cw[5];
        #pragma unroll
        for (int u = 0; u < 5; ++u) cw[u] = cpack[wl * 5 + u];
        const int xid = xs[wl];

        int cb[20];
        #pragma unroll
        for (int p = 0; p < 20; ++p) {
            const int c = (int)((cw[p >> 2] >> ((p & 3) * 8)) & 0xFF);
            cb[p] = c * 600 + oc12;              // byte offset of {kk0,kk1,kk2}
        }

        // phase 1: positions 0..10 (s_0..s_9 need r up to index 10)
        F3 r[11];
        #pragma unroll
        for (int l = 0; l < 11; ++l) r[l] = *(const F3*)(gsb + cb[l]);

        float mx = r[0].y + r[1].z;              // center + next (l=0)
        #pragma unroll
        for (int l = 1; l < 10; ++l) {
            float s = r[l].y + r[l - 1].x + r[l + 1].z;   // (c+p)+n, R8 order
            mx = fmaxf(mx, s);
        }
        const F3 r9 = r[9], r10 = r[10];

        // phase 2: positions 11..19
        F3 qv[9];
        #pragma unroll
        for (int l = 0; l < 9; ++l) qv[l] = *(const F3*)(gsb + cb[11 + l]);

        {   // l = 10
            float s = r10.y + r9.x + qv[0].z;
            mx = fmaxf(mx, s);
        }
        {   // l = 11
            float s = qv[0].y + r10.x + qv[1].z;
            mx = fmaxf(mx, s);
        }
        #pragma unroll
        for (int l = 12; l < 19; ++l) {
            float s = qv[l - 11].y + qv[l - 12].x + qv[l - 10].z;
            mx = fmaxf(mx, s);
        }
        {   // l = 19: center + prev
            float s = qv[8].y + qv[7].x;
            mx = fmaxf(mx, s);
        }

        const float wer = word_emb[(size_t)xid * 50 + oc];
        const float res = mx + cbias + wer;
        const int gw = gw0 + wl;
        const int b = gw / 5, wp = gw - b * 5;
        if (lane < 50)
            ha[b * 256 + wp * 50 + lane] = __float2bfloat16(res);
    }
}

// ---------------------------------------------------------------------------
// Fused fc1 + tanh + fc2-partial. 512 blocks x 512 thr. (R8, verbatim.)
// Block = (rg = bid>>1: 64 rows) x (kh = bid&1: 16 chunks of 128 h-cols).
// Waves 2x4: wr = wv>>2 (row half), wc = wv&3 (col quarter = fc2 k-frag).
// Wave-private hs handoff -> one __syncthreads per chunk (Bs dbuf flip).
// ---------------------------------------------------------------------------
__global__ __launch_bounds__(512, 1) void fused_kernel(
    const __hip_bfloat16* __restrict__ ha, const short* __restrict__ wbf,
    const short* __restrict__ w2bf, float* __restrict__ gpart)
{
    __shared__ char smem[147456];                // 144 KB
    short8* Bsv = (short8*)smem;                 // [2][4096] frags (2x64KB)
    char*   hsb = smem + 131072;                 // 16 KB (16 frags)
    float*  partf = (float*)smem;                // [4][64][64] epilogue alias

    const int tid  = threadIdx.x;
    const int lane = tid & 63;
    const int wv   = tid >> 6;
    const int wr = wv >> 2, wc = wv & 3;
    const int q = lane >> 4, m = lane & 15;
    const int rg = blockIdx.x >> 1, kh = blockIdx.x & 1;
    const int m0 = rg * 64;
    const int q2base = q >> 1, slot = q & 1;

    const short8* wbfv  = (const short8*)wbf;
    const short8* w2bfv = (const short8*)w2bf;
    const short8* hav   = (const short8*)ha;

    // ---- A-frags: wave's 32 rows x K=256: 16 frags = 64 VGPR, pinned ----
    short8 av[2][8];
    #pragma unroll
    for (int mt = 0; mt < 2; ++mt)
        #pragma unroll
        for (int ks = 0; ks < 8; ++ks)
            av[mt][ks] = hav[(size_t)(m0 + wr * 32 + mt * 16 + m) * 32 + ks * 4 + q];
    #pragma unroll
    for (int mt = 0; mt < 2; ++mt)
        #pragma unroll
        for (int ks = 0; ks < 8; ++ks)
            asm volatile("" : "+v"(av[mt][ks]));

    // ---- prologue: stage chunk kh*16 into Bs[0] ----
    #pragma unroll
    for (int i = 0; i < 8; ++i)
        gload_lds16(wbfv + (size_t)(kh * 16) * 4096 + i * 512 + tid,
                    Bsv + i * 512 + tid);
    __syncthreads();

    float4v acc2[2][4] = {};    // fc2 partial: [row-tile mt][out-tile], k = wc

    #pragma unroll 4
    for (int chl = 0; chl < 16; ++chl) {
        const int buf = chl & 1;             // static within unrolled copies
        const int chg = kh * 16 + chl;

        // b2 for this chunk's wave k-frag (kst = chg*4 + wc), issued first
        short8 b2[4];
        #pragma unroll
        for (int Ot = 0; Ot < 4; ++Ot)
            b2[Ot] = w2bfv[(size_t)((chg * 4 + wc) * 4 + Ot) * 64 + lane];

        // async prefetch of next chunk (chl=15 overruns into w2bf: harmless,
        // drained by the final barrier, then overwritten by the epilogue)
        #pragma unroll
        for (int i = 0; i < 8; ++i)
            gload_lds16(wbfv + (size_t)(chg + 1) * 4096 + i * 512 + tid,
                        Bsv + (buf ^ 1) * 4096 + i * 512 + tid);

        // ---- fc1: rows [wr*32,+32) x cols [chg*128 + wc*32, +32) ----
        float4v acc[2][2] = {};
        #pragma unroll
        for (int ks = 0; ks < 8; ++ks) {
            short8 bv[2];
            #pragma unroll
            for (int nt = 0; nt < 2; ++nt)
                bv[nt] = Bsv[buf * 4096 + ((wc * 2 + nt) * 8 + ks) * 64 + lane];
            #pragma unroll
            for (int mt = 0; mt < 2; ++mt)
                #pragma unroll
                for (int nt = 0; nt < 2; ++nt)
                    acc[mt][nt] = __builtin_amdgcn_mfma_f32_16x16x32_bf16(
                        bv[nt], av[mt][ks], acc[mt][nt], 0, 0, 0);
        }

        // ---- tanh + pack to own hs frags (rt = wr*2+mt, kf = wc) ----
        #pragma unroll
        for (int mt = 0; mt < 2; ++mt) {
            const int frag = (wr * 2 + mt) * 4 + wc;
            #pragma unroll
            for (int nt = 0; nt < 2; ++nt) {
                float tv[4];
                #pragma unroll
                for (int r = 0; r < 4; ++r)
                    tv[r] = 1.f - 2.f / (__expf(2.f * acc[mt][nt][r]) + 1.f);
                const int q2 = nt * 2 + q2base;
                const uint p0 = packbf2(tv[0], tv[1]);
                const uint p1 = packbf2(tv[2], tv[3]);
                *(uint2*)(hsb + ((frag * 64 + q2 * 16 + m) * 16 + slot * 8))
                    = make_uint2(p0, p1);
            }
        }

        // ---- fc2 partial: read back OWN frags (same-wave order, no bar) ----
        {
            short8 a2[2];
            #pragma unroll
            for (int mt = 0; mt < 2; ++mt)
                a2[mt] = *(const short8*)(hsb
                    + (((wr * 2 + mt) * 4 + wc) * 64 + lane) * 16);
            #pragma unroll
            for (int mt = 0; mt < 2; ++mt)
                #pragma unroll
                for (int Ot = 0; Ot < 4; ++Ot)
                    acc2[mt][Ot] = __builtin_amdgcn_mfma_f32_16x16x32_bf16(
                        a2[mt], b2[Ot], acc2[mt][Ot], 0, 0, 0);
        }

        // single barrier: Bs[buf] reads done + prefetch vmcnt drained
        __syncthreads();
    }

    // ---- epilogue: spill per-wc k-partials, reduce, write gpart ----
    #pragma unroll
    for (int mt = 0; mt < 2; ++mt)
        #pragma unroll
        for (int Ot = 0; Ot < 4; ++Ot)
            #pragma unroll
            for (int r = 0; r < 4; ++r)
                partf[(size_t)wc * 4096
                      + ((wr * 2 + mt) * 16 + q * 4 + r) * 64 + Ot * 16 + m]
                    = acc2[mt][Ot][r];
    __syncthreads();

    #pragma unroll
    for (int t = 0; t < 8; ++t) {
        int idx = t * 512 + tid;           // row*64 + col
        float s = partf[idx] + partf[4096 + idx]
                + partf[8192 + idx] + partf[12288 + idx];
        gpart[(size_t)blockIdx.x * 4096 + idx] = s;
    }
}

// ---------------------------------------------------------------------------
// combine: sum the two kh halves, + bias, softmax, write out.
// ---------------------------------------------------------------------------
__global__ __launch_bounds__(256) void combine_kernel(
    const float* __restrict__ gpart, const float* __restrict__ fc2_b,
    float* __restrict__ out)
{
    const int tid  = threadIdx.x;
    const int lane = tid & 63;
    const int wv   = tid >> 6;
    const float bias = (lane < 50) ? fc2_b[lane] : 0.f;

    #pragma unroll
    for (int rr = 0; rr < 8; ++rr) {
        const int row = blockIdx.x * 32 + wv * 8 + rr;
        const int rg = row >> 6, rl = row & 63;
        float v = gpart[(size_t)(rg * 2) * 4096 + rl * 64 + lane]
                + gpart[(size_t)(rg * 2 + 1) * 4096 + rl * 64 + lane];
        v = (lane < 50) ? v + bias : -1e30f;
        float mx = v;
        #pragma unroll
        for (int off = 32; off > 0; off >>= 1) mx = fmaxf(mx, __shfl_xor(mx, off));
        float e = __expf(v - mx);
        float s = e;
        #pragma unroll
        for (int off = 32; off > 0; off >>= 1) s += __shfl_xor(s, off);
        if (lane < 50)
            out[(size_t)row * 50 + lane] = e / s;
    }
}

// ---------------------------------------------------------------------------
extern "C" void kernel_launch(void* const* d_in, const int* in_sizes, int n_in,
                              void* d_out, int out_size, void* d_ws, size_t ws_size,
                              hipStream_t stream) {
    const int*   x        = (const int*)  d_in[0];
    const int*   wci      = (const int*)  d_in[1];
    const float* word_emb = (const float*)d_in[2];
    const float* char_emb = (const float*)d_in[3];
    const float* conv_w   = (const float*)d_in[4];
    const float* conv_b   = (const float*)d_in[5];
    const float* fc1_w    = (const float*)d_in[6];
    const float* fc1_b    = (const float*)d_in[7];
    const float* fc2_w    = (const float*)d_in[8];
    const float* fc2_b    = (const float*)d_in[9];
    float* out = (float*)d_out;

    char* ws = (char*)d_ws;
    __hip_bfloat16* ha  = (__hip_bfloat16*)ws;                        // 8 MB
    short* wbf   = (short*)(ws + ((size_t)8  << 20));                 // 2 MB
    short* w2bf  = (short*)(ws + ((size_t)10 << 20));                 // 0.5 MB
    float* gt2   = (float*)(ws + ((size_t)11 << 20));                 // 77 KB
    float* gpart = (float*)(ws + ((size_t)16 << 20));                 // 8 MB

    prep_kernel<<<5579, 256, 0, stream>>>(fc1_w, fc1_b, fc2_w, char_emb,
                                          conv_w, wbf, w2bf, gt2, ha);
    conv_kernel<<<640, 512, 0, stream>>>(x, wci, word_emb, conv_b, gt2, ha);
    fused_kernel<<<512, 512, 0, stream>>>(ha, wbf, w2bf, gpart);
    combine_kernel<<<512, 256, 0, stream>>>(gpart, fc2_b, out);
}

// Round 11
// 193.011 us; speedup vs baseline: 1.1835x; 1.0626x over previous
//
#include <hip/hip_runtime.h>
#include <hip/hip_bf16.h>

// B=16384 W=5 L=20 E=50 V=100000 C=128 H=4096 O=50
// wbf  = bf16 fc1 weights in MFMA A-frag layout:                 ws+8M    (2 MB)
// w2bf = bf16 fc2 weights in MFMA B-frag layout:                 ws+10M   (0.5 MB)
// gt2  = conv table, SPLIT: float2{kk0,kk1}[128][50] at +0 (51200 B)
//        + float{kk2}[128][50] at +51200 (25600 B)               ws+11M   (77 KB)
// R10 post-mortem: conv v1->v2->v3 changed TOTAL by ~0 (rem stable 121-127us
// across all variants) -> conv/prep/combine interiors are NOT the sink; the
// ~85us residual is dispatch overhead: 4 serial launches + ha (8MB) and
// gpart (16MB) round-trips between them.
// R11: 2 launches. conv folded into fused prologue (per-block 320 words,
// table in dead Bs region, results in XOR-swizzled 32KB haS -> av frags);
// full-K per block (grid 256, 32 chunks) + in-kernel softmax epilogue
// (gpart+combine gone). Main loop = R8 proven body verbatim.

typedef __attribute__((ext_vector_type(8))) short short8;
typedef __attribute__((ext_vector_type(4))) float float4v;

__device__ inline short bf16b(float f) {
    __hip_bfloat16 h = __float2bfloat16(f);
    return *reinterpret_cast<short*>(&h);
}
__device__ inline uint packbf2(float a, float b) {
    return (uint)(ushort)bf16b(a) | ((uint)(ushort)bf16b(b) << 16);
}
__device__ inline void gload_lds16(const void* g, void* l) {
    __builtin_amdgcn_global_load_lds(
        (const __attribute__((address_space(1))) unsigned int*)g,
        (__attribute__((address_space(3))) unsigned int*)l, 16, 0, 0);
}

// ---------------------------------------------------------------------------
// Merged prep: wbf (blocks 0..4095), w2bf (..5119), gt2-split (..5194)
// ---------------------------------------------------------------------------
__global__ __launch_bounds__(256) void prep_kernel(
    const float* __restrict__ fc1_w, const float* __restrict__ fc1_b,
    const float* __restrict__ fc2_w, const float* __restrict__ char_emb,
    const float* __restrict__ conv_w, short* __restrict__ wbf,
    short* __restrict__ w2bf, float* __restrict__ gt2)
{
    const int bid = blockIdx.x;
    if (bid < 4096) {                       // fc1 weights+bias -> frag order
        int idx = bid * 256 + threadIdx.x;  // n*256 + k
        int n = idx >> 8, k = idx & 255;
        float v = (k < 250) ? fc1_w[n * 250 + k] : (k == 250 ? fc1_b[n] : 0.f);
        int CT = n >> 4, mm = n & 15;
        int ks = k >> 5, qq = (k >> 3) & 3, j = k & 7;
        wbf[((CT * 8 + ks) * 64 + qq * 16 + mm) * 8 + j] = bf16b(v);
    } else if (bid < 5120) {                // fc2 weights (pad 64) -> frag order
        int idx = (bid - 4096) * 256 + threadIdx.x;   // o*4096 + k
        int o = idx >> 12, k = idx & 4095;
        float v = (o < 50) ? fc2_w[idx] : 0.f;
        int Ot = o >> 4, mm = o & 15;
        int kst = k >> 5, qq = (k >> 3) & 3, j = k & 7;
        w2bf[((kst * 4 + Ot) * 64 + qq * 16 + mm) * 8 + j] = bf16b(v);
    } else {                                // conv table -> split layout
        int idx = (bid - 5120) * 256 + threadIdx.x;   // < 19200
        if (idx >= 19200) return;
        int c = idx / 150, rem = idx - c * 150;
        int kk = rem / 50, o = rem - kk * 50;
        const float* ce = char_emb + c * 50;
        const float* w  = conv_w + o * 150 + kk;
        float s = 0.f;
        #pragma unroll 10
        for (int i = 0; i < 50; ++i) s += ce[i] * w[i * 3];
        if (kk < 2) gt2[(c * 50 + o) * 2 + kk] = s;       // {kk0,kk1} float2
        else        gt2[12800 + c * 50 + o] = s;          // kk2 plane
    }
}

// ---------------------------------------------------------------------------
// Fused conv + fc1 + tanh + fc2 + softmax. 256 blocks x 512 thr, 64 rows.
// LDS map (147456 B total):
//   prologue: Gs table [0,76800) | cpackS [76800,83200) | xsS [83200,84480)
//             haS (64x256 bf16, XOR-swz) [98304,131072)
//   main:     Bs dbuf [0,131072) | hsb [131072,147456)
//   epilogue: partf[4][64][64] fp32 [0,65536)
// Waves 2x4: wr = wv>>2 (row half), wc = wv&3 (col quarter = fc2 k-frag).
// Wave-private hs handoff -> one __syncthreads per chunk (R8-proven).
// ---------------------------------------------------------------------------
__global__ __launch_bounds__(512, 1) void fused_kernel(
    const int* __restrict__ x, const int* __restrict__ wci,
    const float* __restrict__ word_emb, const float* __restrict__ conv_b,
    const float* __restrict__ gt2, const short* __restrict__ wbf,
    const short* __restrict__ w2bf, const float* __restrict__ fc2_b,
    float* __restrict__ out)
{
    __shared__ char smem[147456];
    short8* Bsv   = (short8*)smem;               // main loop: [2][4096] frags
    char*   hsb   = smem + 131072;               // 16 KB
    float*  partf = (float*)smem;                // epilogue alias
    char*   gsb   = smem;                        // prologue: conv table
    uint*   cpackS = (uint*)(smem + 76800);      // 320 x 5
    int*    xsS    = (int*)(smem + 83200);       // 320
    char*   haS    = smem + 98304;               // 64 rows x 512 B, swizzled

    const int tid  = threadIdx.x;
    const int lane = tid & 63;
    const int wv   = tid >> 6;
    const int wr = wv >> 2, wc = wv & 3;
    const int q = lane >> 4, m = lane & 15;
    const int m0 = blockIdx.x * 64;
    const int q2base = q >> 1, slot = q & 1;

    const short8* wbfv  = (const short8*)wbf;
    const short8* w2bfv = (const short8*)w2bf;

    // ================= PROLOGUE: conv for this block's 320 words ==========
    {   // stage split table (76800 B) as float4
        const float4* g4 = (const float4*)gt2;
        float4* s4 = (float4*)gsb;
        #pragma unroll
        for (int i = 0; i < 10; ++i) {
            int idx = i * 512 + tid;
            if (idx < 4800) s4[idx] = g4[idx];
        }
    }
    if (tid < 320) {                             // char ids + xid
        const int xid = x[m0 * 5 + tid];
        xsS[tid] = xid;
        const int* crow = wci + (size_t)xid * 20;
        int cid[20];
        #pragma unroll
        for (int p = 0; p < 20; ++p) cid[p] = crow[p];
        #pragma unroll
        for (int u = 0; u < 5; ++u)
            cpackS[tid * 5 + u] = (uint)cid[u * 4] | ((uint)cid[u * 4 + 1] << 8)
                                | ((uint)cid[u * 4 + 2] << 16) | ((uint)cid[u * 4 + 3] << 24);
    }
    __syncthreads();

    {   // conv: wave wv handles words i*8+wv; lane = out channel
        const int oc = (lane < 50) ? lane : 49;
        const float cbias = conv_b[oc];
        const int oc8 = oc * 8, oc4 = oc * 4;
        for (int i = 0; i < 40; ++i) {
            const int w = i * 8 + wv;
            const int xid = xsS[w];
            const float wer = word_emb[(size_t)xid * 50 + oc];   // early issue
            uint cw[5];
            #pragma unroll
            for (int u = 0; u < 5; ++u) cw[u] = cpackS[w * 5 + u];
            int cc[20];
            #pragma unroll
            for (int p = 0; p < 20; ++p)
                cc[p] = (int)((cw[p >> 2] >> ((p & 3) * 8)) & 0xFF);

            // phase 1: positions 0..10
            float2 r01[11]; float r2[11];
            #pragma unroll
            for (int l = 0; l < 11; ++l) {
                r01[l] = *(const float2*)(gsb + cc[l] * 400 + oc8);
                r2[l]  = *(const float*)(gsb + 51200 + cc[l] * 200 + oc4);
            }
            float mx = r01[0].y + r2[1];                 // R10-passed order
            #pragma unroll
            for (int l = 1; l < 10; ++l) {
                float s = r01[l].y + r01[l - 1].x + r2[l + 1];
                mx = fmaxf(mx, s);
            }
            const float2 r9 = r01[9], r10 = r01[10];

            // phase 2: positions 11..19
            float2 q01[9]; float q2v[9];
            #pragma unroll
            for (int l = 0; l < 9; ++l) {
                q01[l] = *(const float2*)(gsb + cc[11 + l] * 400 + oc8);
                q2v[l] = *(const float*)(gsb + 51200 + cc[11 + l] * 200 + oc4);
            }
            { float s = r10.y + r9.x + q2v[0];  mx = fmaxf(mx, s); }   // l=10
            { float s = q01[0].y + r10.x + q2v[1]; mx = fmaxf(mx, s); } // l=11
            #pragma unroll
            for (int l = 12; l < 19; ++l) {
                float s = q01[l - 11].y + q01[l - 12].x + q2v[l - 10];
                mx = fmaxf(mx, s);
            }
            { float s = q01[8].y + q01[7].x; mx = fmaxf(mx, s); }       // l=19

            if (lane < 50) {
                const int s = w / 5, wp = w - s * 5;
                const int byteoff = (s * 512 + (wp * 50 + oc) * 2) ^ ((s & 7) << 4);
                *(short*)(haS + byteoff) = bf16b(mx + cbias + wer);
            }
        }
    }
    if (tid < 384) {                             // K-bias cols 250..255
        const int s = tid / 6, j = tid - s * 6;
        const int byteoff = (s * 512 + (250 + j) * 2) ^ ((s & 7) << 4);
        *(short*)(haS + byteoff) = bf16b(j == 0 ? 1.f : 0.f);
    }
    __syncthreads();

    // ---- A-frags from haS (swizzled b128 reads): 16 frags = 64 VGPR ----
    short8 av[2][8];
    #pragma unroll
    for (int mt = 0; mt < 2; ++mt)
        #pragma unroll
        for (int ks = 0; ks < 8; ++ks) {
            const int r = wr * 32 + mt * 16 + m;
            const int byteoff = (r * 512 + ks * 64 + q * 16) ^ ((r & 7) << 4);
            av[mt][ks] = *(const short8*)(haS + byteoff);
        }
    #pragma unroll
    for (int mt = 0; mt < 2; ++mt)
        #pragma unroll
        for (int ks = 0; ks < 8; ++ks)
            asm volatile("" : "+v"(av[mt][ks]));
    __syncthreads();                             // haS/Gs dead -> Bs usable

    // ================= MAIN LOOP (R8 body, full K: 32 chunks) =============
    #pragma unroll
    for (int i = 0; i < 8; ++i)
        gload_lds16(wbfv + i * 512 + tid, Bsv + i * 512 + tid);
    __syncthreads();

    float4v acc2[2][4] = {};    // fc2 partial: [row-tile mt][out-tile], k = wc

    #pragma unroll 4
    for (int chg = 0; chg < 32; ++chg) {
        const int buf = chg & 1;

        short8 b2[4];
        #pragma unroll
        for (int Ot = 0; Ot < 4; ++Ot)
            b2[Ot] = w2bfv[(size_t)((chg * 4 + wc) * 4 + Ot) * 64 + lane];

        // async prefetch (chg=31 overruns into w2bf: in-bounds, drained,
        // then overwritten by the partf spill before any read)
        #pragma unroll
        for (int i = 0; i < 8; ++i)
            gload_lds16(wbfv + (size_t)(chg + 1) * 4096 + i * 512 + tid,
                        Bsv + (buf ^ 1) * 4096 + i * 512 + tid);

        // ---- fc1: rows [wr*32,+32) x cols [chg*128 + wc*32, +32) ----
        float4v acc[2][2] = {};
        #pragma unroll
        for (int ks = 0; ks < 8; ++ks) {
            short8 bv[2];
            #pragma unroll
            for (int nt = 0; nt < 2; ++nt)
                bv[nt] = Bsv[buf * 4096 + ((wc * 2 + nt) * 8 + ks) * 64 + lane];
            #pragma unroll
            for (int mt = 0; mt < 2; ++mt)
                #pragma unroll
                for (int nt = 0; nt < 2; ++nt)
                    acc[mt][nt] = __builtin_amdgcn_mfma_f32_16x16x32_bf16(
                        bv[nt], av[mt][ks], acc[mt][nt], 0, 0, 0);
        }

        // ---- tanh + pack to own hs frags (rt = wr*2+mt, kf = wc) ----
        #pragma unroll
        for (int mt = 0; mt < 2; ++mt) {
            const int frag = (wr * 2 + mt) * 4 + wc;
            #pragma unroll
            for (int nt = 0; nt < 2; ++nt) {
                float tv[4];
                #pragma unroll
                for (int r = 0; r < 4; ++r)
                    tv[r] = 1.f - 2.f / (__expf(2.f * acc[mt][nt][r]) + 1.f);
                const int q2 = nt * 2 + q2base;
                const uint p0 = packbf2(tv[0], tv[1]);
                const uint p1 = packbf2(tv[2], tv[3]);
                *(uint2*)(hsb + ((frag * 64 + q2 * 16 + m) * 16 + slot * 8))
                    = make_uint2(p0, p1);
            }
        }

        // ---- fc2 partial: read back OWN frags (same-wave order, no bar) ----
        {
            short8 a2[2];
            #pragma unroll
            for (int mt = 0; mt < 2; ++mt)
                a2[mt] = *(const short8*)(hsb
                    + (((wr * 2 + mt) * 4 + wc) * 64 + lane) * 16);
            #pragma unroll
            for (int mt = 0; mt < 2; ++mt)
                #pragma unroll
                for (int Ot = 0; Ot < 4; ++Ot)
                    acc2[mt][Ot] = __builtin_amdgcn_mfma_f32_16x16x32_bf16(
                        a2[mt], b2[Ot], acc2[mt][Ot], 0, 0, 0);
        }

        __syncthreads();    // Bs[buf] reads done + prefetch vmcnt drained
    }

    // ================= EPILOGUE: reduce + bias + softmax ==================
    #pragma unroll
    for (int mt = 0; mt < 2; ++mt)
        #pragma unroll
        for (int Ot = 0; Ot < 4; ++Ot)
            #pragma unroll
            for (int r = 0; r < 4; ++r)
                partf[(size_t)wc * 4096
                      + ((wr * 2 + mt) * 16 + q * 4 + r) * 64 + Ot * 16 + m]
                    = acc2[mt][Ot][r];
    __syncthreads();

    #pragma unroll
    for (int t = 0; t < 8; ++t) {
        int idx = t * 512 + tid;           // row*64 + col
        int col = idx & 63;
        float lg = partf[idx] + partf[4096 + idx]
                 + partf[8192 + idx] + partf[12288 + idx];
        partf[idx] = (col < 50) ? lg + fc2_b[col] : -1e30f;
    }
    __syncthreads();

    #pragma unroll
    for (int rr = 0; rr < 8; ++rr) {
        const int row = wv * 8 + rr;
        float v = partf[row * 64 + lane];
        float mx = v;
        #pragma unroll
        for (int off = 32; off > 0; off >>= 1) mx = fmaxf(mx, __shfl_xor(mx, off));
        float e = __expf(v - mx);
        float s = e;
        #pragma unroll
        for (int off = 32; off > 0; off >>= 1) s += __shfl_xor(s, off);
        if (lane < 50)
            out[(size_t)(m0 + row) * 50 + lane] = e / s;
    }
}

// ---------------------------------------------------------------------------
extern "C" void kernel_launch(void* const* d_in, const int* in_sizes, int n_in,
                              void* d_out, int out_size, void* d_ws, size_t ws_size,
                              hipStream_t stream) {
    const int*   x        = (const int*)  d_in[0];
    const int*   wci      = (const int*)  d_in[1];
    const float* word_emb = (const float*)d_in[2];
    const float* char_emb = (const float*)d_in[3];
    const float* conv_w   = (const float*)d_in[4];
    const float* conv_b   = (const float*)d_in[5];
    const float* fc1_w    = (const float*)d_in[6];
    const float* fc1_b    = (const float*)d_in[7];
    const float* fc2_w    = (const float*)d_in[8];
    const float* fc2_b    = (const float*)d_in[9];
    float* out = (float*)d_out;

    char* ws = (char*)d_ws;
    short* wbf  = (short*)(ws + ((size_t)8  << 20));                  // 2 MB
    short* w2bf = (short*)(ws + ((size_t)10 << 20));                  // 0.5 MB
    float* gt2  = (float*)(ws + ((size_t)11 << 20));                  // 77 KB

    prep_kernel<<<5195, 256, 0, stream>>>(fc1_w, fc1_b, fc2_w, char_emb,
                                          conv_w, wbf, w2bf, gt2);
    fused_kernel<<<256, 512, 0, stream>>>(x, wci, word_emb, conv_b, gt2,
                                          wbf, w2bf, fc2_b, out);
}

// Round 12
// 192.721 us; speedup vs baseline: 1.1852x; 1.0015x over previous
//
#include <hip/hip_runtime.h>
#include <hip/hip_bf16.h>

// B=16384 W=5 L=20 E=50 V=100000 C=128 H=4096 O=50
// wbf  = bf16 fc1 weights in MFMA A-frag layout:                 ws+8M    (2 MB)
// w2bf = bf16 fc2 weights in MFMA B-frag layout:                 ws+10M   (0.5 MB)
// gt3  = conv table fp32 [128][50][4] = {kk0,kk1,kk2,pad}        ws+11M   (100 KB)
// R11 post-mortem: 2-launch collapse won (193us best) but conv prologue cost
// ~28us, not ~5: (a) 12B taps = 2 LDS instrs/tap -> 12800 instrs/CU ~ 21us
// port issue; (b) per-iter word_emb gather latency serial over 40 iters.
// (31.7ms outlier dispatch = rocprof replay artifact, FETCH 110MB.)
// R12: (1) 16B table -> 1 ds_read_b128/tap (20/word, conflict-free), same
// values + FP order (bit-identical); (2) conv loop = 5 groups x 8 unrolled,
// 8 wer loads prefetched per group (static idx, rule #20 safe); (3) B(0)
// staging issued before av loads (table dead post-barrier), one less barrier.
// Main loop / epilogue / swizzles byte-identical to R11 (passed).

typedef __attribute__((ext_vector_type(8))) short short8;
typedef __attribute__((ext_vector_type(4))) float float4v;

__device__ inline short bf16b(float f) {
    __hip_bfloat16 h = __float2bfloat16(f);
    return *reinterpret_cast<short*>(&h);
}
__device__ inline uint packbf2(float a, float b) {
    return (uint)(ushort)bf16b(a) | ((uint)(ushort)bf16b(b) << 16);
}
__device__ inline void gload_lds16(const void* g, void* l) {
    __builtin_amdgcn_global_load_lds(
        (const __attribute__((address_space(1))) unsigned int*)g,
        (__attribute__((address_space(3))) unsigned int*)l, 16, 0, 0);
}

// ---------------------------------------------------------------------------
// Merged prep: wbf (blocks 0..4095), w2bf (..5119), gt3 (..5194)
// ---------------------------------------------------------------------------
__global__ __launch_bounds__(256) void prep_kernel(
    const float* __restrict__ fc1_w, const float* __restrict__ fc1_b,
    const float* __restrict__ fc2_w, const float* __restrict__ char_emb,
    const float* __restrict__ conv_w, short* __restrict__ wbf,
    short* __restrict__ w2bf, float* __restrict__ gt3)
{
    const int bid = blockIdx.x;
    if (bid < 4096) {                       // fc1 weights+bias -> frag order
        int idx = bid * 256 + threadIdx.x;  // n*256 + k
        int n = idx >> 8, k = idx & 255;
        float v = (k < 250) ? fc1_w[n * 250 + k] : (k == 250 ? fc1_b[n] : 0.f);
        int CT = n >> 4, mm = n & 15;
        int ks = k >> 5, qq = (k >> 3) & 3, j = k & 7;
        wbf[((CT * 8 + ks) * 64 + qq * 16 + mm) * 8 + j] = bf16b(v);
    } else if (bid < 5120) {                // fc2 weights (pad 64) -> frag order
        int idx = (bid - 4096) * 256 + threadIdx.x;   // o*4096 + k
        int o = idx >> 12, k = idx & 4095;
        float v = (o < 50) ? fc2_w[idx] : 0.f;
        int Ot = o >> 4, mm = o & 15;
        int kst = k >> 5, qq = (k >> 3) & 3, j = k & 7;
        w2bf[((kst * 4 + Ot) * 64 + qq * 16 + mm) * 8 + j] = bf16b(v);
    } else {                                // conv table -> [c][o][4] 16B slots
        int idx = (bid - 5120) * 256 + threadIdx.x;   // < 19200
        if (idx >= 19200) return;
        int c = idx / 150, rem = idx - c * 150;
        int kk = rem / 50, o = rem - kk * 50;
        const float* ce = char_emb + c * 50;
        const float* w  = conv_w + o * 150 + kk;
        float s = 0.f;
        #pragma unroll 10
        for (int i = 0; i < 50; ++i) s += ce[i] * w[i * 3];
        gt3[(c * 50 + o) * 4 + kk] = s;
        if (kk == 2) gt3[(c * 50 + o) * 4 + 3] = 0.f;   // pad (never read)
    }
}

// ---------------------------------------------------------------------------
// Fused conv + fc1 + tanh + fc2 + softmax. 256 blocks x 512 thr, 64 rows.
// LDS map (147456 B total):
//   prologue: gt3 table [0,102400) | cpackS [102400,108800) | xsS [..110080)
//             haS (64x256 bf16, XOR-swz) [110080,142848)
//   main:     Bs dbuf [0,131072) | hsb [131072,147456)
//   epilogue: partf[4][64][64] fp32 [0,65536)
// Waves 2x4: wr = wv>>2 (row half), wc = wv&3 (col quarter = fc2 k-frag).
// Wave-private hs handoff -> one __syncthreads per chunk (R8-proven).
// ---------------------------------------------------------------------------
__global__ __launch_bounds__(512, 1) void fused_kernel(
    const int* __restrict__ x, const int* __restrict__ wci,
    const float* __restrict__ word_emb, const float* __restrict__ conv_b,
    const float* __restrict__ gt3, const short* __restrict__ wbf,
    const short* __restrict__ w2bf, const float* __restrict__ fc2_b,
    float* __restrict__ out)
{
    __shared__ char smem[147456];
    short8* Bsv   = (short8*)smem;               // main loop: [2][4096] frags
    char*   hsb   = smem + 131072;               // 16 KB
    float*  partf = (float*)smem;                // epilogue alias
    char*   gsb   = smem;                        // prologue: conv table
    uint*   cpackS = (uint*)(smem + 102400);     // 320 x 5
    int*    xsS    = (int*)(smem + 108800);      // 320
    char*   haS    = smem + 110080;              // 64 rows x 512 B, swizzled

    const int tid  = threadIdx.x;
    const int lane = tid & 63;
    const int wv   = tid >> 6;
    const int wr = wv >> 2, wc = wv & 3;
    const int q = lane >> 4, m = lane & 15;
    const int m0 = blockIdx.x * 64;
    const int q2base = q >> 1, slot = q & 1;

    const short8* wbfv  = (const short8*)wbf;
    const short8* w2bfv = (const short8*)w2bf;

    // ================= PROLOGUE: conv for this block's 320 words ==========
    {   // stage 16B-slot table (102400 B) as float4
        const float4* g4 = (const float4*)gt3;
        float4* s4 = (float4*)gsb;
        #pragma unroll
        for (int i = 0; i < 13; ++i) {
            int idx = i * 512 + tid;
            if (idx < 6400) s4[idx] = g4[idx];
        }
    }
    if (tid < 320) {                             // char ids + xid
        const int xid = x[m0 * 5 + tid];
        xsS[tid] = xid;
        const int* crow = wci + (size_t)xid * 20;
        int cid[20];
        #pragma unroll
        for (int p = 0; p < 20; ++p) cid[p] = crow[p];
        #pragma unroll
        for (int u = 0; u < 5; ++u)
            cpackS[tid * 5 + u] = (uint)cid[u * 4] | ((uint)cid[u * 4 + 1] << 8)
                                | ((uint)cid[u * 4 + 2] << 16) | ((uint)cid[u * 4 + 3] << 24);
    }
    __syncthreads();

    {   // conv: wave wv handles words (g*8+j)*8+wv; lane = out channel
        const int oc = (lane < 50) ? lane : 49;
        const float cbias = conv_b[oc];
        const int oc16 = oc * 16;
        for (int g = 0; g < 5; ++g) {
            float werv[8];                       // 8 gathers in flight (MLP)
            #pragma unroll
            for (int j = 0; j < 8; ++j) {
                const int w = (g * 8 + j) * 8 + wv;
                werv[j] = word_emb[(size_t)xsS[w] * 50 + oc];
            }
            #pragma unroll
            for (int j = 0; j < 8; ++j) {
                const int w = (g * 8 + j) * 8 + wv;
                uint cw[5];
                #pragma unroll
                for (int u = 0; u < 5; ++u) cw[u] = cpackS[w * 5 + u];
                int cb[20];
                #pragma unroll
                for (int p = 0; p < 20; ++p) {
                    const int c = (int)((cw[p >> 2] >> ((p & 3) * 8)) & 0xFF);
                    cb[p] = c * 800 + oc16;      // byte offset of 16B slot
                }
                // phase 1: positions 0..10 (one b128 per tap)
                float4 r[11];
                #pragma unroll
                for (int l = 0; l < 11; ++l) r[l] = *(const float4*)(gsb + cb[l]);
                float mx = r[0].y + r[1].z;      // R10/R11-passed order
                #pragma unroll
                for (int l = 1; l < 10; ++l) {
                    float s = r[l].y + r[l - 1].x + r[l + 1].z;
                    mx = fmaxf(mx, s);
                }
                const float4 r9 = r[9], r10 = r[10];
                // phase 2: positions 11..19
                float4 qv[9];
                #pragma unroll
                for (int l = 0; l < 9; ++l) qv[l] = *(const float4*)(gsb + cb[11 + l]);
                { float s = r10.y + r9.x + qv[0].z;    mx = fmaxf(mx, s); }  // l=10
                { float s = qv[0].y + r10.x + qv[1].z; mx = fmaxf(mx, s); }  // l=11
                #pragma unroll
                for (int l = 12; l < 19; ++l) {
                    float s = qv[l - 11].y + qv[l - 12].x + qv[l - 10].z;
                    mx = fmaxf(mx, s);
                }
                { float s = qv[8].y + qv[7].x; mx = fmaxf(mx, s); }          // l=19

                if (lane < 50) {
                    const int s = w / 5, wp = w - s * 5;
                    const int byteoff = (s * 512 + (wp * 50 + oc) * 2) ^ ((s & 7) << 4);
                    *(short*)(haS + byteoff) = bf16b(mx + cbias + werv[j]);
                }
            }
        }
    }
    if (tid < 384) {                             // K-bias cols 250..255
        const int s = tid / 6, j = tid - s * 6;
        const int byteoff = (s * 512 + (250 + j) * 2) ^ ((s & 7) << 4);
        *(short*)(haS + byteoff) = bf16b(j == 0 ? 1.f : 0.f);
    }
    __syncthreads();                             // conv done; table dead

    // issue B(0) staging now (overlaps av loads; table region is dead)
    #pragma unroll
    for (int i = 0; i < 8; ++i)
        gload_lds16(wbfv + i * 512 + tid, Bsv + i * 512 + tid);

    // ---- A-frags from haS (swizzled b128 reads): 16 frags = 64 VGPR ----
    short8 av[2][8];
    #pragma unroll
    for (int mt = 0; mt < 2; ++mt)
        #pragma unroll
        for (int ks = 0; ks < 8; ++ks) {
            const int r = wr * 32 + mt * 16 + m;
            const int byteoff = (r * 512 + ks * 64 + q * 16) ^ ((r & 7) << 4);
            av[mt][ks] = *(const short8*)(haS + byteoff);
        }
    #pragma unroll
    for (int mt = 0; mt < 2; ++mt)
        #pragma unroll
        for (int ks = 0; ks < 8; ++ks)
            asm volatile("" : "+v"(av[mt][ks]));
    __syncthreads();                             // drains vmcnt: B(0) ready

    // ================= MAIN LOOP (R8 body, full K: 32 chunks) =============
    float4v acc2[2][4] = {};    // fc2 partial: [row-tile mt][out-tile], k = wc

    #pragma unroll 4
    for (int chg = 0; chg < 32; ++chg) {
        const int buf = chg & 1;

        short8 b2[4];
        #pragma unroll
        for (int Ot = 0; Ot < 4; ++Ot)
            b2[Ot] = w2bfv[(size_t)((chg * 4 + wc) * 4 + Ot) * 64 + lane];

        // async prefetch (chg=31 overruns into w2bf: in-bounds, drained,
        // then overwritten by the partf spill before any read)
        #pragma unroll
        for (int i = 0; i < 8; ++i)
            gload_lds16(wbfv + (size_t)(chg + 1) * 4096 + i * 512 + tid,
                        Bsv + (buf ^ 1) * 4096 + i * 512 + tid);

        // ---- fc1: rows [wr*32,+32) x cols [chg*128 + wc*32, +32) ----
        float4v acc[2][2] = {};
        #pragma unroll
        for (int ks = 0; ks < 8; ++ks) {
            short8 bv[2];
            #pragma unroll
            for (int nt = 0; nt < 2; ++nt)
                bv[nt] = Bsv[buf * 4096 + ((wc * 2 + nt) * 8 + ks) * 64 + lane];
            #pragma unroll
            for (int mt = 0; mt < 2; ++mt)
                #pragma unroll
                for (int nt = 0; nt < 2; ++nt)
                    acc[mt][nt] = __builtin_amdgcn_mfma_f32_16x16x32_bf16(
                        bv[nt], av[mt][ks], acc[mt][nt], 0, 0, 0);
        }

        // ---- tanh + pack to own hs frags (rt = wr*2+mt, kf = wc) ----
        #pragma unroll
        for (int mt = 0; mt < 2; ++mt) {
            const int frag = (wr * 2 + mt) * 4 + wc;
            #pragma unroll
            for (int nt = 0; nt < 2; ++nt) {
                float tv[4];
                #pragma unroll
                for (int r = 0; r < 4; ++r)
                    tv[r] = 1.f - 2.f / (__expf(2.f * acc[mt][nt][r]) + 1.f);
                const int q2 = nt * 2 + q2base;
                const uint p0 = packbf2(tv[0], tv[1]);
                const uint p1 = packbf2(tv[2], tv[3]);
                *(uint2*)(hsb + ((frag * 64 + q2 * 16 + m) * 16 + slot * 8))
                    = make_uint2(p0, p1);
            }
        }

        // ---- fc2 partial: read back OWN frags (same-wave order, no bar) ----
        {
            short8 a2[2];
            #pragma unroll
            for (int mt = 0; mt < 2; ++mt)
                a2[mt] = *(const short8*)(hsb
                    + (((wr * 2 + mt) * 4 + wc) * 64 + lane) * 16);
            #pragma unroll
            for (int mt = 0; mt < 2; ++mt)
                #pragma unroll
                for (int Ot = 0; Ot < 4; ++Ot)
                    acc2[mt][Ot] = __builtin_amdgcn_mfma_f32_16x16x32_bf16(
                        a2[mt], b2[Ot], acc2[mt][Ot], 0, 0, 0);
        }

        __syncthreads();    // Bs[buf] reads done + prefetch vmcnt drained
    }

    // ================= EPILOGUE: reduce + bias + softmax ==================
    #pragma unroll
    for (int mt = 0; mt < 2; ++mt)
        #pragma unroll
        for (int Ot = 0; Ot < 4; ++Ot)
            #pragma unroll
            for (int r = 0; r < 4; ++r)
                partf[(size_t)wc * 4096
                      + ((wr * 2 + mt) * 16 + q * 4 + r) * 64 + Ot * 16 + m]
                    = acc2[mt][Ot][r];
    __syncthreads();

    #pragma unroll
    for (int t = 0; t < 8; ++t) {
        int idx = t * 512 + tid;           // row*64 + col
        int col = idx & 63;
        float lg = partf[idx] + partf[4096 + idx]
                 + partf[8192 + idx] + partf[12288 + idx];
        partf[idx] = (col < 50) ? lg + fc2_b[col] : -1e30f;
    }
    __syncthreads();

    #pragma unroll
    for (int rr = 0; rr < 8; ++rr) {
        const int row = wv * 8 + rr;
        float v = partf[row * 64 + lane];
        float mx = v;
        #pragma unroll
        for (int off = 32; off > 0; off >>= 1) mx = fmaxf(mx, __shfl_xor(mx, off));
        float e = __expf(v - mx);
        float s = e;
        #pragma unroll
        for (int off = 32; off > 0; off >>= 1) s += __shfl_xor(s, off);
        if (lane < 50)
            out[(size_t)(m0 + row) * 50 + lane] = e / s;
    }
}

// ---------------------------------------------------------------------------
extern "C" void kernel_launch(void* const* d_in, const int* in_sizes, int n_in,
                              void* d_out, int out_size, void* d_ws, size_t ws_size,
                              hipStream_t stream) {
    const int*   x        = (const int*)  d_in[0];
    const int*   wci      = (const int*)  d_in[1];
    const float* word_emb = (const float*)d_in[2];
    const float* char_emb = (const float*)d_in[3];
    const float* conv_w   = (const float*)d_in[4];
    const float* conv_b   = (const float*)d_in[5];
    const float* fc1_w    = (const float*)d_in[6];
    const float* fc1_b    = (const float*)d_in[7];
    const float* fc2_w    = (const float*)d_in[8];
    const float* fc2_b    = (const float*)d_in[9];
    float* out = (float*)d_out;

    char* ws = (char*)d_ws;
    short* wbf  = (short*)(ws + ((size_t)8  << 20));                  // 2 MB
    short* w2bf = (short*)(ws + ((size_t)10 << 20));                  // 0.5 MB
    float* gt3  = (float*)(ws + ((size_t)11 << 20));                  // 100 KB

    prep_kernel<<<5195, 256, 0, stream>>>(fc1_w, fc1_b, fc2_w, char_emb,
                                          conv_w, wbf, w2bf, gt3);
    fused_kernel<<<256, 512, 0, stream>>>(x, wci, word_emb, conv_b, gt3,
                                          wbf, w2bf, fc2_b, out);
}